// Round 2
// baseline (909.639 us; speedup 1.0000x reference)
//
#include <hip/hip_runtime.h>
#include <hip/hip_bf16.h>

#define D 128

typedef __attribute__((ext_vector_type(8))) short bf16x8;
typedef __attribute__((ext_vector_type(4))) float f32x4;

__device__ __forceinline__ unsigned short f2bf_bits(float f) {
    union { __hip_bfloat16 h; unsigned short u; } c;
    c.h = __float2bfloat16(f);
    return c.u;
}
__device__ __forceinline__ float bfbits2f(unsigned short u) {
    return __uint_as_float(((unsigned)u) << 16);
}
// flag=1 -> underlying data is float32; flag=0 -> bf16
__device__ __forceinline__ float ldf(const void* p, size_t i, int f32) {
    return f32 ? ((const float*)p)[i] : bfbits2f(((const unsigned short*)p)[i]);
}
__device__ __forceinline__ void unpk(unsigned u, float& a, float& b) {
    a = __uint_as_float(u << 16);
    b = __uint_as_float(u & 0xFFFF0000u);
}

// ---- K0: dtype detection. bf16 view of f32 data has wild exponents. ----
__global__ void detect_kernel(const void* node, int* flag) {
    int t = threadIdx.x;
    int bad = 0;
    for (int j = 0; j < 4; j++) {
        float v = bfbits2f(((const unsigned short*)node)[t + 64 * j]);
        if (!(fabsf(v) < 1e4f)) bad = 1;  // catches huge and NaN
    }
    unsigned long long m = __ballot(bad);
    if (t == 0) *flag = (m != 0ull) ? 1 : 0;
}

__global__ void zero_kernel(int* a, int n) {
    int i = blockIdx.x * blockDim.x + threadIdx.x;
    int s = gridDim.x * blockDim.x;
    for (int j = i; j < n; j += s) a[j] = 0;
}

// ---- K1: wsqAll[m] = w_trip[m] @ w_quad, bf16 out ----
__global__ void wq_kernel(const void* w_trip, const void* w_quad,
                          unsigned short* wsqAll, const int* flag) {
    int f32 = *flag;
    int k = blockIdx.x, m = blockIdx.y, t = threadIdx.x;
    float acc = 0.f;
    for (int j = 0; j < D; j++)
        acc += ldf(w_trip, (size_t)m * D * D + (size_t)k * D + j, f32) *
               ldf(w_quad, (size_t)j * D + t, f32);
    wsqAll[m * D * D + k * D + t] = f2bf_bits(acc);
}

// ---- K2: table GEMMs O(rows,128) = A @ W, bf16 out. 6 jobs via blockIdx.y ----
__global__ __launch_bounds__(256) void gemm_kernel(
    const void* node, const void* rel, const void* w_trip,
    const unsigned short* wsqAll,
    unsigned short* nodeWs, unsigned short* nodeWd,
    unsigned short* nodeWsq, unsigned short* nodeWdq,
    unsigned short* relWr, unsigned short* relWrq,
    const int* flag, int N, int R) {
    int f32 = *flag;
    const void* A; const void* Wb; size_t woff; int wf;
    unsigned short* O; int rows;
    switch (blockIdx.y) {
        case 0: A = node; Wb = w_trip; woff = 0;         wf = f32; O = nodeWs;  rows = N; break;
        case 1: A = node; Wb = w_trip; woff = 2 * D * D; wf = f32; O = nodeWd;  rows = N; break;
        case 2: A = node; Wb = wsqAll; woff = 0;         wf = 0;   O = nodeWsq; rows = N; break;
        case 3: A = node; Wb = wsqAll; woff = 2 * D * D; wf = 0;   O = nodeWdq; rows = N; break;
        case 4: A = rel;  Wb = w_trip; woff = D * D;     wf = f32; O = relWr;   rows = R; break;
        default: A = rel; Wb = wsqAll; woff = D * D;     wf = 0;   O = relWrq;  rows = R; break;
    }
    int row0 = blockIdx.x * 64;
    if (row0 >= rows) return;

    __shared__ __align__(16) unsigned short Wt[D][D + 8];  // Wt[n][k] = W[k][n]
    int tid = threadIdx.y * 64 + threadIdx.x;
    for (int idx = tid; idx < D * D; idx += 256) {
        int k = idx >> 7, n = idx & 127;
        unsigned short b = wf ? f2bf_bits(((const float*)Wb)[woff + idx])
                              : ((const unsigned short*)Wb)[woff + idx];
        Wt[n][k] = b;
    }
    __syncthreads();

    int lane = threadIdx.x, wv = threadIdx.y;
    int l16 = lane & 15, quad = lane >> 4;
    int ar = row0 + wv * 16 + l16;
    int ar_c = ar < rows ? ar : rows - 1;

    f32x4 acc[8];
#pragma unroll
    for (int i = 0; i < 8; i++) acc[i] = (f32x4){0.f, 0.f, 0.f, 0.f};

#pragma unroll
    for (int kk = 0; kk < 4; kk++) {
        int k = kk * 32 + quad * 8;
        bf16x8 af;
        if (f32) {
            const float* Af = (const float*)A + (size_t)ar_c * D + k;
#pragma unroll
            for (int j = 0; j < 8; j++) af[j] = (short)f2bf_bits(Af[j]);
        } else {
            af = *(const bf16x8*)((const unsigned short*)A + (size_t)ar_c * D + k);
        }
#pragma unroll
        for (int nt = 0; nt < 8; nt++) {
            bf16x8 bfr = *(const bf16x8*)(&Wt[nt * 16 + l16][k]);
            acc[nt] = __builtin_amdgcn_mfma_f32_16x16x32_bf16(af, bfr, acc[nt], 0, 0, 0);
        }
    }
    // C/D: col = lane&15, row = quad*4 + reg
    int cr0 = row0 + wv * 16 + quad * 4;
#pragma unroll
    for (int nt = 0; nt < 8; nt++) {
        int cn = nt * 16 + l16;
#pragma unroll
        for (int r = 0; r < 4; r++) {
            int cr = cr0 + r;
            if (cr < rows) O[(size_t)cr * D + cn] = f2bf_bits(acc[nt][r]);
        }
    }
}

// ---- K3: CSR build ----
__global__ void count_kernel(const int* __restrict__ dst, int* __restrict__ cnt, int E) {
    int e = blockIdx.x * blockDim.x + threadIdx.x;
    if (e < E) atomicAdd(&cnt[dst[e]], 1);
}

__global__ void scan_kernel(const int* __restrict__ cnt, int* __restrict__ offs, int N) {
    __shared__ int sh[256];
    __shared__ int carrySh;
    int tid = threadIdx.x;
    if (tid == 0) carrySh = 0;
    __syncthreads();
    for (int base = 0; base < N; base += 256) {
        int i = base + tid;
        int v = (i < N) ? cnt[i] : 0;
        sh[tid] = v;
        __syncthreads();
        for (int o = 1; o < 256; o <<= 1) {
            int t2 = (tid >= o) ? sh[tid - o] : 0;
            __syncthreads();
            sh[tid] += t2;
            __syncthreads();
        }
        int incl = sh[tid];
        int carry = carrySh;
        if (i < N) offs[i] = carry + incl - v;
        __syncthreads();
        if (tid == 255) carrySh = carry + incl;
        __syncthreads();
    }
    if (tid == 0) offs[N] = carrySh;
}

__global__ void scatter_kernel(const int* __restrict__ src, const int* __restrict__ dst,
                               const int* __restrict__ et, const int* __restrict__ offs,
                               int* __restrict__ cur, int* __restrict__ srcS,
                               int* __restrict__ etS, int E) {
    int e = blockIdx.x * blockDim.x + threadIdx.x;
    if (e >= E) return;
    int d = dst[e];
    int pos = offs[d] + atomicAdd(&cur[d], 1);
    srcS[pos] = src[e];
    etS[pos] = et[e];
}

// ---- K4: wave-per-node aggregation + loop GEMV + layernorm + store ----
// Softmax without max-shift: logits bounded (~|a|<20), exp safe in f32,
// mathematically identical to reference (shift invariance).
__global__ __launch_bounds__(256) void agg_kernel(
    const int* __restrict__ offs, const int* __restrict__ srcS, const int* __restrict__ etS,
    const unsigned short* __restrict__ qsT, const unsigned short* __restrict__ qrT,
    const unsigned short* __restrict__ qdT,
    const unsigned short* __restrict__ tsT, const unsigned short* __restrict__ trT,
    const unsigned short* __restrict__ tdT,
    const void* __restrict__ node, const void* __restrict__ normv,
    const void* __restrict__ loopW, const void* __restrict__ evoW,
    void* __restrict__ out, const int* __restrict__ flag, int N) {
    int n = blockIdx.x * 4 + threadIdx.y;
    if (n >= N) return;
    int f32 = *flag;
    int lane = threadIdx.x;
    int start = offs[n], end = offs[n + 1];
    int deg = end - start;

    float qd0, qd1, td0, td1;
    unpk(((const unsigned*)qdT)[(size_t)n * 64 + lane], qd0, qd1);
    unpk(((const unsigned*)tdT)[(size_t)n * 64 + lane], td0, td1);

    float den0 = 0.f, den1 = 0.f, h0 = 0.f, h1 = 0.f;
    for (int e = start; e < end; e++) {
        int s = srcS[e], r = etS[e];
        float qs0, qs1, qr0, qr1, ts0, ts1, tr0, tr1;
        unpk(((const unsigned*)qsT)[(size_t)s * 64 + lane], qs0, qs1);
        unpk(((const unsigned*)qrT)[(size_t)r * 64 + lane], qr0, qr1);
        unpk(((const unsigned*)tsT)[(size_t)s * 64 + lane], ts0, ts1);
        unpk(((const unsigned*)trT)[(size_t)r * 64 + lane], tr0, tr1);
        float q0 = qs0 + qr0 + qd0, q1 = qs1 + qr1 + qd1;
        float a0 = q0 > 0.f ? q0 : 0.01f * q0;
        float a1 = q1 > 0.f ? q1 : 0.01f * q1;
        float e0 = __expf(a0), e1 = __expf(a1);
        den0 += e0; den1 += e1;
        h0 += e0 * (ts0 + tr0 + td0);
        h1 += e1 * (ts1 + tr1 + td1);
    }

    // loop term: node[n] @ (deg>0 ? loopW : evolveW), features 2*lane, 2*lane+1
    const void* Wm = (deg > 0) ? loopW : evoW;
    float acc0 = 0.f, acc1 = 0.f;
    for (int k = 0; k < D; k++) {
        float nv = ldf(node, (size_t)n * D + k, f32);
        acc0 += nv * ldf(Wm, (size_t)k * D + 2 * lane, f32);
        acc1 += nv * ldf(Wm, (size_t)k * D + 2 * lane + 1, f32);
    }

    float x0, x1;
    if (deg > 0) {
        float nrm = ldf(normv, n, f32);
        x0 = h0 / den0 * nrm + acc0;
        x1 = h1 / den1 * nrm + acc1;
    } else {
        x0 = acc0;
        x1 = acc1;
    }

    float s = x0 + x1, ss = x0 * x0 + x1 * x1;
#pragma unroll
    for (int o = 32; o; o >>= 1) {
        s += __shfl_xor(s, o);
        ss += __shfl_xor(ss, o);
    }
    float mu = s * (1.f / 128.f);
    float var = ss * (1.f / 128.f) - mu * mu;
    float rstd = rsqrtf(var + 1e-5f);
    float y0 = (x0 - mu) * rstd, y1 = (x1 - mu) * rstd;

    if (f32) {
        ((float2*)out)[(size_t)n * 64 + lane] = make_float2(y0, y1);
    } else {
        unsigned ob = (unsigned)f2bf_bits(y0) | ((unsigned)f2bf_bits(y1) << 16);
        ((unsigned*)out)[(size_t)n * 64 + lane] = ob;
    }
}

extern "C" void kernel_launch(void* const* d_in, const int* in_sizes, int n_in,
                              void* d_out, int out_size, void* d_ws, size_t ws_size,
                              hipStream_t stream) {
    const void* node = d_in[0];
    const void* rel = d_in[1];
    const void* normv = d_in[2];
    const void* wtrip = d_in[3];
    const void* wquad = d_in[4];
    const void* loopW = d_in[5];
    const void* evoW = d_in[6];
    const int* src = (const int*)d_in[7];
    const int* dst = (const int*)d_in[8];
    const int* et = (const int*)d_in[9];

    int N = in_sizes[0] / D;
    int R = in_sizes[1] / D;
    int E = in_sizes[7];
    size_t ND = (size_t)N * D;

    char* p = (char*)d_ws;
    auto alloc = [&](size_t bytes) -> void* {
        void* r = (void*)p;
        p += (bytes + 255) & ~(size_t)255;
        return r;
    };
    unsigned short* nodeWs = (unsigned short*)alloc(ND * 2);
    unsigned short* nodeWd = (unsigned short*)alloc(ND * 2);
    unsigned short* nodeWsq = (unsigned short*)alloc(ND * 2);
    unsigned short* nodeWdq = (unsigned short*)alloc(ND * 2);
    unsigned short* relWr = (unsigned short*)alloc((size_t)R * D * 2);
    unsigned short* relWrq = (unsigned short*)alloc((size_t)R * D * 2);
    unsigned short* wsqAll = (unsigned short*)alloc((size_t)3 * D * D * 2);
    int* cnt = (int*)alloc((size_t)2 * N * 4);  // cnt | cur
    int* offs = (int*)alloc((size_t)(N + 1) * 4);
    int* srcS = (int*)alloc((size_t)E * 4);
    int* etS = (int*)alloc((size_t)E * 4);
    int* flag = (int*)alloc(4);

    detect_kernel<<<1, 64, 0, stream>>>(node, flag);
    zero_kernel<<<256, 256, 0, stream>>>(cnt, 2 * N);
    wq_kernel<<<dim3(D, 3), D, 0, stream>>>(wtrip, wquad, wsqAll, flag);
    gemm_kernel<<<dim3((N + 63) / 64, 6), dim3(64, 4), 0, stream>>>(
        node, rel, wtrip, wsqAll,
        nodeWs, nodeWd, nodeWsq, nodeWdq, relWr, relWrq, flag, N, R);
    count_kernel<<<(E + 255) / 256, 256, 0, stream>>>(dst, cnt, E);
    scan_kernel<<<1, 256, 0, stream>>>(cnt, offs, N);
    scatter_kernel<<<(E + 255) / 256, 256, 0, stream>>>(src, dst, et, offs, cnt + N,
                                                        srcS, etS, E);
    agg_kernel<<<(N + 3) / 4, dim3(64, 4), 0, stream>>>(
        offs, srcS, etS, nodeWsq, relWrq, nodeWdq, nodeWs, relWr, nodeWd,
        node, normv, loopW, evoW, d_out, flag, N);
}

// Round 3
// 362.089 us; speedup vs baseline: 2.5122x; 2.5122x over previous
//
#include <hip/hip_runtime.h>
#include <hip/hip_bf16.h>

#define D 128

typedef __attribute__((ext_vector_type(8))) short bf16x8;
typedef __attribute__((ext_vector_type(4))) float f32x4;

__device__ __forceinline__ unsigned short f2bf_bits(float f) {
    union { __hip_bfloat16 h; unsigned short u; } c;
    c.h = __float2bfloat16(f);
    return c.u;
}
__device__ __forceinline__ float bfbits2f(unsigned short u) {
    return __uint_as_float(((unsigned)u) << 16);
}
// flag=1 -> underlying data is float32; flag=0 -> bf16
__device__ __forceinline__ float ldf(const void* p, size_t i, int f32) {
    return f32 ? ((const float*)p)[i] : bfbits2f(((const unsigned short*)p)[i]);
}
__device__ __forceinline__ void unpk(unsigned u, float& a, float& b) {
    a = __uint_as_float(u << 16);
    b = __uint_as_float(u & 0xFFFF0000u);
}

// ---- K0: dtype detection. bf16 view of f32 data has wild exponents. ----
__global__ void detect_kernel(const void* node, int* flag) {
    int t = threadIdx.x;
    int bad = 0;
    for (int j = 0; j < 4; j++) {
        float v = bfbits2f(((const unsigned short*)node)[t + 64 * j]);
        if (!(fabsf(v) < 1e4f)) bad = 1;  // catches huge and NaN
    }
    unsigned long long m = __ballot(bad);
    if (t == 0) *flag = (m != 0ull) ? 1 : 0;
}

__global__ void zero_kernel(int* a, int n) {
    int i = blockIdx.x * blockDim.x + threadIdx.x;
    int s = gridDim.x * blockDim.x;
    for (int j = i; j < n; j += s) a[j] = 0;
}

// ---- K1: wsqAll[m] = w_trip[m] @ w_quad, bf16 out ----
__global__ void wq_kernel(const void* w_trip, const void* w_quad,
                          unsigned short* wsqAll, const int* flag) {
    int f32 = *flag;
    int k = blockIdx.x, m = blockIdx.y, t = threadIdx.x;
    float acc = 0.f;
    for (int j = 0; j < D; j++)
        acc += ldf(w_trip, (size_t)m * D * D + (size_t)k * D + j, f32) *
               ldf(w_quad, (size_t)j * D + t, f32);
    wsqAll[m * D * D + k * D + t] = f2bf_bits(acc);
}

// ---- K2: table GEMMs O(rows,128) = A @ W, bf16 out. 8 jobs via blockIdx.y ----
__global__ __launch_bounds__(256) void gemm_kernel(
    const void* node, const void* rel, const void* w_trip,
    const void* loopW, const void* evoW, const unsigned short* wsqAll,
    unsigned short* nodeWs, unsigned short* nodeWd,
    unsigned short* nodeWsq, unsigned short* nodeWdq,
    unsigned short* relWr, unsigned short* relWrq,
    unsigned short* loopA, unsigned short* loopB,
    const int* flag, int N, int R) {
    int f32 = *flag;
    const void* A; const void* Wb; size_t woff; int wf;
    unsigned short* O; int rows;
    switch (blockIdx.y) {
        case 0: A = node; Wb = w_trip; woff = 0;         wf = f32; O = nodeWs;  rows = N; break;
        case 1: A = node; Wb = w_trip; woff = 2 * D * D; wf = f32; O = nodeWd;  rows = N; break;
        case 2: A = node; Wb = wsqAll; woff = 0;         wf = 0;   O = nodeWsq; rows = N; break;
        case 3: A = node; Wb = wsqAll; woff = 2 * D * D; wf = 0;   O = nodeWdq; rows = N; break;
        case 4: A = node; Wb = loopW;  woff = 0;         wf = f32; O = loopA;   rows = N; break;
        case 5: A = node; Wb = evoW;   woff = 0;         wf = f32; O = loopB;   rows = N; break;
        case 6: A = rel;  Wb = w_trip; woff = D * D;     wf = f32; O = relWr;   rows = R; break;
        default: A = rel; Wb = wsqAll; woff = D * D;     wf = 0;   O = relWrq;  rows = R; break;
    }
    int row0 = blockIdx.x * 64;
    if (row0 >= rows) return;

    __shared__ __align__(16) unsigned short Wt[D][D + 8];  // Wt[n][k] = W[k][n]
    int tid = threadIdx.y * 64 + threadIdx.x;
    for (int idx = tid; idx < D * D; idx += 256) {
        int k = idx >> 7, n = idx & 127;
        unsigned short b = wf ? f2bf_bits(((const float*)Wb)[woff + idx])
                              : ((const unsigned short*)Wb)[woff + idx];
        Wt[n][k] = b;
    }
    __syncthreads();

    int lane = threadIdx.x, wv = threadIdx.y;
    int l16 = lane & 15, quad = lane >> 4;
    int ar = row0 + wv * 16 + l16;
    int ar_c = ar < rows ? ar : rows - 1;

    f32x4 acc[8];
#pragma unroll
    for (int i = 0; i < 8; i++) acc[i] = (f32x4){0.f, 0.f, 0.f, 0.f};

#pragma unroll
    for (int kk = 0; kk < 4; kk++) {
        int k = kk * 32 + quad * 8;
        bf16x8 af;
        if (f32) {
            const float* Af = (const float*)A + (size_t)ar_c * D + k;
#pragma unroll
            for (int j = 0; j < 8; j++) af[j] = (short)f2bf_bits(Af[j]);
        } else {
            af = *(const bf16x8*)((const unsigned short*)A + (size_t)ar_c * D + k);
        }
#pragma unroll
        for (int nt = 0; nt < 8; nt++) {
            bf16x8 bfr = *(const bf16x8*)(&Wt[nt * 16 + l16][k]);
            acc[nt] = __builtin_amdgcn_mfma_f32_16x16x32_bf16(af, bfr, acc[nt], 0, 0, 0);
        }
    }
    // C/D: col = lane&15, row = quad*4 + reg
    int cr0 = row0 + wv * 16 + quad * 4;
#pragma unroll
    for (int nt = 0; nt < 8; nt++) {
        int cn = nt * 16 + l16;
#pragma unroll
        for (int r = 0; r < 4; r++) {
            int cr = cr0 + r;
            if (cr < rows) O[(size_t)cr * D + cn] = f2bf_bits(acc[nt][r]);
        }
    }
}

// ---- K3: CSR build ----
__global__ void count_kernel(const int* __restrict__ dst, int* __restrict__ cnt, int E) {
    int e = blockIdx.x * blockDim.x + threadIdx.x;
    if (e < E) atomicAdd(&cnt[dst[e]], 1);
}

// hierarchical exclusive scan: per-block scan -> scan of block totals -> add
__global__ void scan_block(const int* __restrict__ cnt, int* __restrict__ offs,
                           int* __restrict__ part, int N) {
    __shared__ int sh[256];
    int tid = threadIdx.x;
    int i = blockIdx.x * 256 + tid;
    int v = (i < N) ? cnt[i] : 0;
    sh[tid] = v;
    __syncthreads();
    for (int o = 1; o < 256; o <<= 1) {
        int t = (tid >= o) ? sh[tid - o] : 0;
        __syncthreads();
        sh[tid] += t;
        __syncthreads();
    }
    if (i < N) offs[i] = sh[tid] - v;
    if (tid == 255) part[blockIdx.x] = sh[255];
}

__global__ void scan_part(int* __restrict__ part, int nb) {
    __shared__ int sh[256];
    int tid = threadIdx.x;
    int v = (tid < nb) ? part[tid] : 0;
    sh[tid] = v;
    __syncthreads();
    for (int o = 1; o < 256; o <<= 1) {
        int t = (tid >= o) ? sh[tid - o] : 0;
        __syncthreads();
        sh[tid] += t;
        __syncthreads();
    }
    if (tid < nb) part[tid] = sh[tid] - v;  // exclusive
}

__global__ void scan_add(int* __restrict__ offs, const int* __restrict__ part,
                         int N, int E) {
    int i = blockIdx.x * 256 + threadIdx.x;
    if (i < N) offs[i] += part[blockIdx.x];
    if (i == 0) offs[N] = E;
}

__global__ void scatter_kernel(const int* __restrict__ src, const int* __restrict__ dst,
                               const int* __restrict__ et, const int* __restrict__ offs,
                               int* __restrict__ cur, int* __restrict__ srcS,
                               int* __restrict__ etS, int E) {
    int e = blockIdx.x * blockDim.x + threadIdx.x;
    if (e >= E) return;
    int d = dst[e];
    int pos = offs[d] + atomicAdd(&cur[d], 1);
    srcS[pos] = src[e];
    etS[pos] = et[e];
}

// ---- K4: wave-per-node aggregation + layernorm + store ----
// Softmax without max-shift: logits bounded, exp safe in f32, identical by
// shift invariance. Edge indices preloaded 64-at-a-time and broadcast via shfl.
__global__ __launch_bounds__(256) void agg_kernel(
    const int* __restrict__ offs, const int* __restrict__ srcS, const int* __restrict__ etS,
    const unsigned* __restrict__ qsT, const unsigned* __restrict__ qrT,
    const unsigned* __restrict__ qdT,
    const unsigned* __restrict__ tsT, const unsigned* __restrict__ trT,
    const unsigned* __restrict__ tdT,
    const unsigned* __restrict__ loopA, const unsigned* __restrict__ loopB,
    const void* __restrict__ normv,
    void* __restrict__ out, const int* __restrict__ flag, int N) {
    int n = blockIdx.x * 4 + threadIdx.y;
    if (n >= N) return;
    int f32 = *flag;
    int lane = threadIdx.x;
    int start = offs[n], end = offs[n + 1];
    int deg = end - start;

    float qd0, qd1, td0, td1;
    unpk(qdT[(size_t)n * 64 + lane], qd0, qd1);
    unpk(tdT[(size_t)n * 64 + lane], td0, td1);

    float den0 = 0.f, den1 = 0.f, h0 = 0.f, h1 = 0.f;

    for (int e0 = start; e0 < end; e0 += 64) {
        int m = end - e0;
        if (m > 64) m = 64;
        int sv = 0, rv = 0;
        if (lane < m) {
            sv = srcS[e0 + lane];
            rv = etS[e0 + lane];
        }
        int j = 0;
#define EDGE_LOADS(J, S, R, UQS, UQR, UTS, UTR)                       \
        int S = __shfl(sv, (J)), R = __shfl(rv, (J));                 \
        unsigned UQS = qsT[(size_t)(S)*64 + lane];                    \
        unsigned UQR = qrT[(size_t)(R)*64 + lane];                    \
        unsigned UTS = tsT[(size_t)(S)*64 + lane];                    \
        unsigned UTR = trT[(size_t)(R)*64 + lane];
#define EDGE_MATH(UQS, UQR, UTS, UTR)                                 \
        {                                                             \
            float qs0, qs1, qr0, qr1, ts0, ts1, tr0, tr1;             \
            unpk(UQS, qs0, qs1); unpk(UQR, qr0, qr1);                 \
            unpk(UTS, ts0, ts1); unpk(UTR, tr0, tr1);                 \
            float q0 = qs0 + qr0 + qd0, q1 = qs1 + qr1 + qd1;         \
            float a0 = q0 > 0.f ? q0 : 0.01f * q0;                    \
            float a1 = q1 > 0.f ? q1 : 0.01f * q1;                    \
            float ex0 = __expf(a0), ex1 = __expf(a1);                 \
            den0 += ex0; den1 += ex1;                                 \
            h0 += ex0 * (ts0 + tr0 + td0);                            \
            h1 += ex1 * (ts1 + tr1 + td1);                            \
        }
        for (; j + 3 < m; j += 4) {
            EDGE_LOADS(j + 0, sA, rA, qsA, qrA, tsA, trA)
            EDGE_LOADS(j + 1, sB, rB, qsB, qrB, tsB, trB)
            EDGE_LOADS(j + 2, sC, rC, qsC, qrC, tsC, trC)
            EDGE_LOADS(j + 3, sD, rD, qsD, qrD, tsD, trD)
            EDGE_MATH(qsA, qrA, tsA, trA)
            EDGE_MATH(qsB, qrB, tsB, trB)
            EDGE_MATH(qsC, qrC, tsC, trC)
            EDGE_MATH(qsD, qrD, tsD, trD)
        }
        for (; j < m; j++) {
            EDGE_LOADS(j, sA, rA, qsA, qrA, tsA, trA)
            EDGE_MATH(qsA, qrA, tsA, trA)
        }
    }

    // loop term (precomputed tables)
    unsigned ul = (deg > 0) ? loopA[(size_t)n * 64 + lane] : loopB[(size_t)n * 64 + lane];
    float acc0, acc1;
    unpk(ul, acc0, acc1);

    float x0, x1;
    if (deg > 0) {
        float nrm = ldf(normv, n, f32);
        x0 = h0 / den0 * nrm + acc0;
        x1 = h1 / den1 * nrm + acc1;
    } else {
        x0 = acc0;
        x1 = acc1;
    }

    float s = x0 + x1, ss = x0 * x0 + x1 * x1;
#pragma unroll
    for (int o = 32; o; o >>= 1) {
        s += __shfl_xor(s, o);
        ss += __shfl_xor(ss, o);
    }
    float mu = s * (1.f / 128.f);
    float var = ss * (1.f / 128.f) - mu * mu;
    float rstd = rsqrtf(var + 1e-5f);
    float y0 = (x0 - mu) * rstd, y1 = (x1 - mu) * rstd;

    if (f32) {
        ((float2*)out)[(size_t)n * 64 + lane] = make_float2(y0, y1);
    } else {
        unsigned ob = (unsigned)f2bf_bits(y0) | ((unsigned)f2bf_bits(y1) << 16);
        ((unsigned*)out)[(size_t)n * 64 + lane] = ob;
    }
}

extern "C" void kernel_launch(void* const* d_in, const int* in_sizes, int n_in,
                              void* d_out, int out_size, void* d_ws, size_t ws_size,
                              hipStream_t stream) {
    const void* node = d_in[0];
    const void* rel = d_in[1];
    const void* normv = d_in[2];
    const void* wtrip = d_in[3];
    const void* wquad = d_in[4];
    const void* loopW = d_in[5];
    const void* evoW = d_in[6];
    const int* src = (const int*)d_in[7];
    const int* dst = (const int*)d_in[8];
    const int* et = (const int*)d_in[9];

    int N = in_sizes[0] / D;
    int R = in_sizes[1] / D;
    int E = in_sizes[7];
    size_t ND = (size_t)N * D;
    int nb = (N + 255) / 256;

    char* p = (char*)d_ws;
    auto alloc = [&](size_t bytes) -> void* {
        void* r = (void*)p;
        p += (bytes + 255) & ~(size_t)255;
        return r;
    };
    unsigned short* nodeWs = (unsigned short*)alloc(ND * 2);
    unsigned short* nodeWd = (unsigned short*)alloc(ND * 2);
    unsigned short* nodeWsq = (unsigned short*)alloc(ND * 2);
    unsigned short* nodeWdq = (unsigned short*)alloc(ND * 2);
    unsigned short* loopA = (unsigned short*)alloc(ND * 2);
    unsigned short* loopB = (unsigned short*)alloc(ND * 2);
    unsigned short* relWr = (unsigned short*)alloc((size_t)R * D * 2);
    unsigned short* relWrq = (unsigned short*)alloc((size_t)R * D * 2);
    unsigned short* wsqAll = (unsigned short*)alloc((size_t)3 * D * D * 2);
    int* cnt = (int*)alloc((size_t)2 * N * 4);  // cnt | cur
    int* offs = (int*)alloc((size_t)(N + 1) * 4);
    int* part = (int*)alloc((size_t)(nb + 1) * 4);
    int* srcS = (int*)alloc((size_t)E * 4);
    int* etS = (int*)alloc((size_t)E * 4);
    int* flag = (int*)alloc(4);

    detect_kernel<<<1, 64, 0, stream>>>(node, flag);
    zero_kernel<<<256, 256, 0, stream>>>(cnt, 2 * N);
    wq_kernel<<<dim3(D, 3), D, 0, stream>>>(wtrip, wquad, wsqAll, flag);
    gemm_kernel<<<dim3((N + 63) / 64, 8), dim3(64, 4), 0, stream>>>(
        node, rel, wtrip, loopW, evoW, wsqAll,
        nodeWs, nodeWd, nodeWsq, nodeWdq, relWr, relWrq, loopA, loopB, flag, N, R);
    count_kernel<<<(E + 255) / 256, 256, 0, stream>>>(dst, cnt, E);
    scan_block<<<nb, 256, 0, stream>>>(cnt, offs, part, N);
    scan_part<<<1, 256, 0, stream>>>(part, nb);
    scan_add<<<nb, 256, 0, stream>>>(offs, part, N, E);
    scatter_kernel<<<(E + 255) / 256, 256, 0, stream>>>(src, dst, et, offs, cnt + N,
                                                        srcS, etS, E);
    agg_kernel<<<(N + 3) / 4, dim3(64, 4), 0, stream>>>(
        offs, srcS, etS,
        (const unsigned*)nodeWsq, (const unsigned*)relWrq, (const unsigned*)nodeWdq,
        (const unsigned*)nodeWs, (const unsigned*)relWr, (const unsigned*)nodeWd,
        (const unsigned*)loopA, (const unsigned*)loopB,
        normv, d_out, flag, N);
}

// Round 6
// 330.556 us; speedup vs baseline: 2.7518x; 1.0954x over previous
//
#include <hip/hip_runtime.h>
#include <hip/hip_bf16.h>

#define D 128

typedef __attribute__((ext_vector_type(8))) short bf16x8;
typedef __attribute__((ext_vector_type(4))) float f32x4;

__device__ __forceinline__ unsigned short f2bf_bits(float f) {
    union { __hip_bfloat16 h; unsigned short u; } c;
    c.h = __float2bfloat16(f);
    return c.u;
}
__device__ __forceinline__ float bfbits2f(unsigned short u) {
    return __uint_as_float(((unsigned)u) << 16);
}
__device__ __forceinline__ float ldf(const void* p, size_t i, int f32) {
    return f32 ? ((const float*)p)[i] : bfbits2f(((const unsigned short*)p)[i]);
}
__device__ __forceinline__ void unpk(unsigned u, float& a, float& b) {
    a = __uint_as_float(u << 16);
    b = __uint_as_float(u & 0xFFFF0000u);
}

// ---- K0: dtype detection ----
__global__ void detect_kernel(const void* node, int* flag) {
    int t = threadIdx.x;
    int bad = 0;
    for (int j = 0; j < 4; j++) {
        float v = bfbits2f(((const unsigned short*)node)[t + 64 * j]);
        if (!(fabsf(v) < 1e4f)) bad = 1;
    }
    unsigned long long m = __ballot(bad);
    if (t == 0) *flag = (m != 0ull) ? 1 : 0;
}

__global__ void zero_kernel(int* a, int n) {
    int i = blockIdx.x * blockDim.x + threadIdx.x;
    int s = gridDim.x * blockDim.x;
    for (int j = i; j < n; j += s) a[j] = 0;
}

// ---- K1: wsqAll[m] = w_trip[m] @ w_quad, bf16 ----
__global__ void wq_kernel(const void* w_trip, const void* w_quad,
                          unsigned short* wsqAll, const int* flag) {
    int f32 = *flag;
    int k = blockIdx.x, m = blockIdx.y, t = threadIdx.x;
    float acc = 0.f;
    for (int j = 0; j < D; j++)
        acc += ldf(w_trip, (size_t)m * D * D + (size_t)k * D + j, f32) *
               ldf(w_quad, (size_t)j * D + t, f32);
    wsqAll[m * D * D + k * D + t] = f2bf_bits(acc);
}

// ---- K1b: build 8 transposed bf16 weights wT[j][n][k] = W_j[k][n] ----
// j: 0 Wsq_s 1 W_s 2 Wsq_d 3 W_d 4 loopW 5 evoW 6 Wsq_r 7 W_r
__global__ void trans_kernel(const void* wtrip, const void* loopW, const void* evoW,
                             const unsigned short* wsqAll, unsigned short* wT,
                             const int* flag) {
    int j = blockIdx.x;
    int f32 = *flag;
    const void* srcp; size_t base; int isbf;
    switch (j) {
        case 0: srcp = wsqAll; base = 0;         isbf = 1;    break;
        case 1: srcp = wtrip;  base = 0;         isbf = !f32; break;
        case 2: srcp = wsqAll; base = 2 * D * D; isbf = 1;    break;
        case 3: srcp = wtrip;  base = 2 * D * D; isbf = !f32; break;
        case 4: srcp = loopW;  base = 0;         isbf = !f32; break;
        case 5: srcp = evoW;   base = 0;         isbf = !f32; break;
        case 6: srcp = wsqAll; base = D * D;     isbf = 1;    break;
        default: srcp = wtrip; base = D * D;     isbf = !f32; break;
    }
    for (int idx = threadIdx.x; idx < D * D; idx += blockDim.x) {
        int n = idx >> 7, k = idx & 127;
        unsigned short b;
        if (isbf) b = ((const unsigned short*)srcp)[base + (size_t)k * D + n];
        else      b = f2bf_bits(((const float*)srcp)[base + (size_t)k * D + n]);
        wT[(size_t)j * D * D + (size_t)n * D + k] = b;
    }
}

// ---- K2: fused table GEMM. One block = 64 rows; A fragments loaded once.
// R3-proven staging (padded Wt) + R3-proven scalar u16 stores.
// Interleaved tables (per row, 256 u16): Q feat c -> 4*(c>>1)+(c&1),
//                                        T feat c -> 4*(c>>1)+2+(c&1).
__global__ __launch_bounds__(256) void gemm_kernel(
    const void* __restrict__ node, const void* __restrict__ rel,
    const unsigned short* __restrict__ wT, const int* __restrict__ cnt,
    unsigned short* __restrict__ nodeST, unsigned short* __restrict__ nodeDT,
    unsigned short* __restrict__ relRT, unsigned short* __restrict__ loopSel,
    const int* __restrict__ flag, int N, int R, int nodeBlocks) {
    __shared__ __align__(16) unsigned short Wt[D][D + 8];

    int f32 = *flag;
    int bx = blockIdx.x;
    int isRel = bx >= nodeBlocks;
    int rows = isRel ? R : N;
    int row0 = (isRel ? bx - nodeBlocks : bx) * 64;
    const void* A = isRel ? rel : node;

    int tid = threadIdx.y * 64 + threadIdx.x;
    int lane = threadIdx.x, wv = threadIdx.y;
    int l16 = lane & 15, quad = lane >> 4;
    int ar = row0 + wv * 16 + l16;
    int ar_c = ar < rows ? ar : rows - 1;

    bf16x8 af[4];
#pragma unroll
    for (int kk = 0; kk < 4; kk++) {
        int k = kk * 32 + quad * 8;
        if (f32) {
            const float* Af = (const float*)A + (size_t)ar_c * D + k;
#pragma unroll
            for (int j = 0; j < 8; j++) af[kk][j] = (short)f2bf_bits(Af[j]);
        } else {
            af[kk] = *(const bf16x8*)((const unsigned short*)A + (size_t)ar_c * D + k);
        }
    }

    int cr0 = row0 + wv * 16 + quad * 4;
    f32x4 accHold[8];  // loopW result held across the evoW pass

    int jBeg = isRel ? 6 : 0, jEnd = isRel ? 8 : 6;
    for (int j = jBeg; j < jEnd; j++) {
        // stage wT[j] into padded LDS (pre-transposed: direct vector copy)
        const unsigned short* g = wT + (size_t)j * D * D;
        for (int c = tid; c < 2048; c += 256) {
            int n = c >> 4, kb = c & 15;
            *(bf16x8*)(&Wt[n][kb * 8]) = *(const bf16x8*)(g + n * 128 + kb * 8);
        }
        __syncthreads();

        f32x4 acc[8];
#pragma unroll
        for (int i = 0; i < 8; i++) acc[i] = (f32x4){0.f, 0.f, 0.f, 0.f};
#pragma unroll
        for (int kk = 0; kk < 4; kk++) {
#pragma unroll
            for (int nt = 0; nt < 8; nt++) {
                bf16x8 bfr = *(const bf16x8*)(&Wt[nt * 16 + l16][kk * 32 + quad * 8]);
                acc[nt] = __builtin_amdgcn_mfma_f32_16x16x32_bf16(af[kk], bfr, acc[nt], 0, 0, 0);
            }
        }
        __syncthreads();  // all reads of Wt done before next stage overwrites

        if (j == 4) {
#pragma unroll
            for (int i = 0; i < 8; i++) accHold[i] = acc[i];
        } else if (j == 5) {
            // deg-select loopW vs evoW, store plain 128-u16 rows
#pragma unroll
            for (int r = 0; r < 4; r++) {
                int cr = cr0 + r;
                if (cr < rows) {
                    int deg = cnt[cr];
#pragma unroll
                    for (int nt = 0; nt < 8; nt++) {
                        int cn = nt * 16 + l16;
                        float v = (deg > 0) ? accHold[nt][r] : acc[nt][r];
                        loopSel[(size_t)cr * 128 + cn] = f2bf_bits(v);
                    }
                }
            }
        } else {
            unsigned short* O; int tsel;
            switch (j) {
                case 0: O = nodeST; tsel = 0; break;
                case 1: O = nodeST; tsel = 1; break;
                case 2: O = nodeDT; tsel = 0; break;
                case 3: O = nodeDT; tsel = 1; break;
                case 6: O = relRT;  tsel = 0; break;
                default: O = relRT; tsel = 1; break;
            }
#pragma unroll
            for (int nt = 0; nt < 8; nt++) {
                int cn = nt * 16 + l16;
                int widx = 4 * (cn >> 1) + (cn & 1) + (tsel ? 2 : 0);
#pragma unroll
                for (int r = 0; r < 4; r++) {
                    int cr = cr0 + r;
                    if (cr < rows)
                        O[(size_t)cr * 256 + widx] = f2bf_bits(acc[nt][r]);
                }
            }
        }
    }
}

// ---- K3: CSR build ----
__global__ void count_kernel(const int* __restrict__ dst, int* __restrict__ cnt, int E) {
    int e = blockIdx.x * blockDim.x + threadIdx.x;
    if (e < E) atomicAdd(&cnt[dst[e]], 1);
}

__global__ void scan_block(const int* __restrict__ cnt, int* __restrict__ offs,
                           int* __restrict__ part, int N) {
    __shared__ int sh[256];
    int tid = threadIdx.x;
    int i = blockIdx.x * 256 + tid;
    int v = (i < N) ? cnt[i] : 0;
    sh[tid] = v;
    __syncthreads();
    for (int o = 1; o < 256; o <<= 1) {
        int t = (tid >= o) ? sh[tid - o] : 0;
        __syncthreads();
        sh[tid] += t;
        __syncthreads();
    }
    if (i < N) offs[i] = sh[tid] - v;
    if (tid == 255) part[blockIdx.x] = sh[255];
}

__global__ void scan_part(int* __restrict__ part, int nb) {
    __shared__ int sh[256];
    int tid = threadIdx.x;
    int v = (tid < nb) ? part[tid] : 0;
    sh[tid] = v;
    __syncthreads();
    for (int o = 1; o < 256; o <<= 1) {
        int t = (tid >= o) ? sh[tid - o] : 0;
        __syncthreads();
        sh[tid] += t;
        __syncthreads();
    }
    if (tid < nb) part[tid] = sh[tid] - v;
}

__global__ void scan_add(int* __restrict__ offs, const int* __restrict__ part,
                         int N, int E) {
    int i = blockIdx.x * 256 + threadIdx.x;
    if (i < N) offs[i] += part[blockIdx.x];
    if (i == 0) offs[N] = E;
}

__global__ void scatter_kernel(const int* __restrict__ src, const int* __restrict__ dst,
                               const int* __restrict__ et, const int* __restrict__ offs,
                               int* __restrict__ cur, unsigned* __restrict__ ePack, int E) {
    int e = blockIdx.x * blockDim.x + threadIdx.x;
    if (e >= E) return;
    int d = dst[e];
    int pos = offs[d] + atomicAdd(&cur[d], 1);
    ePack[pos] = (unsigned)src[e] | ((unsigned)et[e] << 20);
}

// ---- K4: wave-per-node aggregation + layernorm ----
__global__ __launch_bounds__(256) void agg_kernel(
    const int* __restrict__ offs, const unsigned* __restrict__ ePack,
    const uint2* __restrict__ ST, const uint2* __restrict__ RT,
    const uint2* __restrict__ DT, const unsigned* __restrict__ loopSel,
    const void* __restrict__ normv, void* __restrict__ out,
    const int* __restrict__ flag, int N) {
    int n = blockIdx.x * 4 + threadIdx.y;
    if (n >= N) return;
    int f32 = *flag;
    int lane = threadIdx.x;
    int start = offs[n], end = offs[n + 1];
    int deg = end - start;

    unsigned ul = loopSel[(size_t)n * 64 + lane];
    uint2 ud = DT[(size_t)n * 64 + lane];
    float qd0, qd1, td0, td1, acc0, acc1;
    unpk(ud.x, qd0, qd1);
    unpk(ud.y, td0, td1);
    unpk(ul, acc0, acc1);

    float den0 = 0.f, den1 = 0.f, h0 = 0.f, h1 = 0.f;
    for (int e0 = start; e0 < end; e0 += 64) {
        int m = end - e0;
        if (m > 64) m = 64;
        unsigned pk = (lane < m) ? ePack[e0 + lane] : 0u;
        int j = 0;
#define EDGE_LOADS(J, US, UR)                                         \
        unsigned pk_##US = __shfl(pk, (J));                           \
        uint2 US = ST[(size_t)(pk_##US & 0xFFFFFu) * 64 + lane];      \
        uint2 UR = RT[(size_t)(pk_##US >> 20) * 64 + lane];
#define EDGE_MATH(US, UR)                                             \
        {                                                             \
            float qs0, qs1, qr0, qr1, ts0, ts1, tr0, tr1;             \
            unpk(US.x, qs0, qs1); unpk(UR.x, qr0, qr1);               \
            unpk(US.y, ts0, ts1); unpk(UR.y, tr0, tr1);               \
            float q0 = qs0 + qr0 + qd0, q1 = qs1 + qr1 + qd1;         \
            float a0 = q0 > 0.f ? q0 : 0.01f * q0;                    \
            float a1 = q1 > 0.f ? q1 : 0.01f * q1;                    \
            float ex0 = __expf(a0), ex1 = __expf(a1);                 \
            den0 += ex0; den1 += ex1;                                 \
            h0 += ex0 * (ts0 + tr0 + td0);                            \
            h1 += ex1 * (ts1 + tr1 + td1);                            \
        }
        for (; j + 3 < m; j += 4) {
            EDGE_LOADS(j + 0, uA, rA)
            EDGE_LOADS(j + 1, uB, rB)
            EDGE_LOADS(j + 2, uC, rC)
            EDGE_LOADS(j + 3, uD, rD)
            EDGE_MATH(uA, rA)
            EDGE_MATH(uB, rB)
            EDGE_MATH(uC, rC)
            EDGE_MATH(uD, rD)
        }
        for (; j < m; j++) {
            EDGE_LOADS(j, uE, rE)
            EDGE_MATH(uE, rE)
        }
    }

    float x0, x1;
    if (deg > 0) {
        float nrm = ldf(normv, n, f32);
        x0 = h0 / den0 * nrm + acc0;
        x1 = h1 / den1 * nrm + acc1;
    } else {
        x0 = acc0;
        x1 = acc1;
    }

    float s = x0 + x1, ss = x0 * x0 + x1 * x1;
#pragma unroll
    for (int o = 32; o; o >>= 1) {
        s += __shfl_xor(s, o);
        ss += __shfl_xor(ss, o);
    }
    float mu = s * (1.f / 128.f);
    float var = ss * (1.f / 128.f) - mu * mu;
    float rstd = rsqrtf(var + 1e-5f);
    float y0 = (x0 - mu) * rstd, y1 = (x1 - mu) * rstd;

    if (f32) {
        ((float2*)out)[(size_t)n * 64 + lane] = make_float2(y0, y1);
    } else {
        unsigned ob = (unsigned)f2bf_bits(y0) | ((unsigned)f2bf_bits(y1) << 16);
        ((unsigned*)out)[(size_t)n * 64 + lane] = ob;
    }
}

extern "C" void kernel_launch(void* const* d_in, const int* in_sizes, int n_in,
                              void* d_out, int out_size, void* d_ws, size_t ws_size,
                              hipStream_t stream) {
    const void* node = d_in[0];
    const void* rel = d_in[1];
    const void* normv = d_in[2];
    const void* wtrip = d_in[3];
    const void* wquad = d_in[4];
    const void* loopW = d_in[5];
    const void* evoW = d_in[6];
    const int* src = (const int*)d_in[7];
    const int* dst = (const int*)d_in[8];
    const int* et = (const int*)d_in[9];

    int N = in_sizes[0] / D;
    int R = in_sizes[1] / D;
    int E = in_sizes[7];
    int nb = (N + 255) / 256;
    int nodeBlocks = (N + 63) / 64;
    int relBlocks = (R + 63) / 64;

    char* p = (char*)d_ws;
    auto alloc = [&](size_t bytes) -> void* {
        void* r = (void*)p;
        p += (bytes + 255) & ~(size_t)255;
        return r;
    };
    unsigned short* nodeST = (unsigned short*)alloc((size_t)N * 256 * 2);
    unsigned short* nodeDT = (unsigned short*)alloc((size_t)N * 256 * 2);
    unsigned short* relRT = (unsigned short*)alloc((size_t)R * 256 * 2);
    unsigned short* loopSel = (unsigned short*)alloc((size_t)N * 128 * 2);
    unsigned short* wsqAll = (unsigned short*)alloc((size_t)3 * D * D * 2);
    unsigned short* wT = (unsigned short*)alloc((size_t)8 * D * D * 2);
    int* cnt = (int*)alloc((size_t)2 * N * 4);  // cnt | cur
    int* offs = (int*)alloc((size_t)(N + 1) * 4);
    int* part = (int*)alloc((size_t)(nb + 1) * 4);
    unsigned* ePack = (unsigned*)alloc((size_t)E * 4);
    int* flag = (int*)alloc(4);

    detect_kernel<<<1, 64, 0, stream>>>(node, flag);
    zero_kernel<<<256, 256, 0, stream>>>(cnt, 2 * N);
    wq_kernel<<<dim3(D, 3), D, 0, stream>>>(wtrip, wquad, wsqAll, flag);
    trans_kernel<<<8, 256, 0, stream>>>(wtrip, loopW, evoW, wsqAll, wT, flag);
    count_kernel<<<(E + 255) / 256, 256, 0, stream>>>(dst, cnt, E);
    gemm_kernel<<<nodeBlocks + relBlocks, dim3(64, 4), 0, stream>>>(
        node, rel, wT, cnt, nodeST, nodeDT, relRT, loopSel, flag, N, R, nodeBlocks);
    scan_block<<<nb, 256, 0, stream>>>(cnt, offs, part, N);
    scan_part<<<1, 256, 0, stream>>>(part, nb);
    scan_add<<<nb, 256, 0, stream>>>(offs, part, N, E);
    scatter_kernel<<<(E + 255) / 256, 256, 0, stream>>>(src, dst, et, offs, cnt + N,
                                                        ePack, E);
    agg_kernel<<<(N + 3) / 4, dim3(64, 4), 0, stream>>>(
        offs, ePack, (const uint2*)nodeST, (const uint2*)relRT, (const uint2*)nodeDT,
        (const unsigned*)loopSel, normv, d_out, flag, N);
}

// Round 7
// 286.227 us; speedup vs baseline: 3.1780x; 1.1549x over previous
//
#include <hip/hip_runtime.h>
#include <hip/hip_bf16.h>

#define D 128

typedef __attribute__((ext_vector_type(8))) short bf16x8;
typedef __attribute__((ext_vector_type(4))) float f32x4;

__device__ __forceinline__ unsigned short f2bf_bits(float f) {
    union { __hip_bfloat16 h; unsigned short u; } c;
    c.h = __float2bfloat16(f);
    return c.u;
}
__device__ __forceinline__ float bfbits2f(unsigned short u) {
    return __uint_as_float(((unsigned)u) << 16);
}
__device__ __forceinline__ float ldf(const void* p, size_t i, int f32) {
    return f32 ? ((const float*)p)[i] : bfbits2f(((const unsigned short*)p)[i]);
}
__device__ __forceinline__ void unpk(unsigned u, float& a, float& b) {
    a = __uint_as_float(u << 16);
    b = __uint_as_float(u & 0xFFFF0000u);
}

// ---- K0: dtype detect (block 0) + zero counters ----
__global__ void init_kernel(const void* node, int* flag, int* a, int n) {
    if (blockIdx.x == 0 && threadIdx.x < 64) {
        int t = threadIdx.x;
        int bad = 0;
        for (int j = 0; j < 4; j++) {
            float v = bfbits2f(((const unsigned short*)node)[t + 64 * j]);
            if (!(fabsf(v) < 1e4f)) bad = 1;
        }
        unsigned long long m = __ballot(bad);
        if (t == 0) *flag = (m != 0ull) ? 1 : 0;
    }
    int i = blockIdx.x * blockDim.x + threadIdx.x;
    int s = gridDim.x * blockDim.x;
    for (int j = i; j < n; j += s) a[j] = 0;
}

// ---- K1: wsqAll[m] = w_trip[m] @ w_quad, bf16 ----
__global__ void wq_kernel(const void* w_trip, const void* w_quad,
                          unsigned short* wsqAll, const int* flag) {
    int f32 = *flag;
    int k = blockIdx.x, m = blockIdx.y, t = threadIdx.x;
    float acc = 0.f;
    for (int j = 0; j < D; j++)
        acc += ldf(w_trip, (size_t)m * D * D + (size_t)k * D + j, f32) *
               ldf(w_quad, (size_t)j * D + t, f32);
    wsqAll[m * D * D + k * D + t] = f2bf_bits(acc);
}

// ---- K1b: build 8 transposed bf16 weights wT[j][n][k] = W_j[k][n] ----
// j: 0 Wsq_s 1 W_s 2 Wsq_d 3 W_d 4 loopW 5 evoW 6 Wsq_r 7 W_r
__global__ void trans_kernel(const void* wtrip, const void* loopW, const void* evoW,
                             const unsigned short* wsqAll, unsigned short* wT,
                             const int* flag) {
    int j = blockIdx.x;
    int f32 = *flag;
    const void* srcp; size_t base; int isbf;
    switch (j) {
        case 0: srcp = wsqAll; base = 0;         isbf = 1;    break;
        case 1: srcp = wtrip;  base = 0;         isbf = !f32; break;
        case 2: srcp = wsqAll; base = 2 * D * D; isbf = 1;    break;
        case 3: srcp = wtrip;  base = 2 * D * D; isbf = !f32; break;
        case 4: srcp = loopW;  base = 0;         isbf = !f32; break;
        case 5: srcp = evoW;   base = 0;         isbf = !f32; break;
        case 6: srcp = wsqAll; base = D * D;     isbf = 1;    break;
        default: srcp = wtrip; base = D * D;     isbf = !f32; break;
    }
    for (int c = threadIdx.x; c < 1024; c += blockDim.x) {
        int idx = blockIdx.y * 1024 + c;
        int n = idx >> 7, k = idx & 127;
        unsigned short b;
        if (isbf) b = ((const unsigned short*)srcp)[base + (size_t)k * D + n];
        else      b = f2bf_bits(((const float*)srcp)[base + (size_t)k * D + n]);
        wT[(size_t)j * D * D + (size_t)n * D + k] = b;
    }
}

// ---- K2: fused table GEMM. One block = 64 rows; A fragments loaded once.
// Jobs run in (Q,T) pairs; epilogue packs bf16 pairs via shfl_xor(1) and
// stores coalesced u32 words. Table layout (u32 words, 128/row):
//   word 2p   = Q(2p) | Q(2p+1)<<16
//   word 2p+1 = T(2p) | T(2p+1)<<16
// identical bits to R6's u16 interleave — agg unchanged.
__global__ __launch_bounds__(256) void gemm_kernel(
    const void* __restrict__ node, const void* __restrict__ rel,
    const unsigned short* __restrict__ wT, const int* __restrict__ cnt,
    unsigned* __restrict__ nodeST, unsigned* __restrict__ nodeDT,
    unsigned* __restrict__ relRT, unsigned* __restrict__ loopSel,
    const int* __restrict__ flag, int N, int R, int nodeBlocks) {
    __shared__ __align__(16) unsigned short Wt[D][D + 8];

    int f32 = *flag;
    int bx = blockIdx.x;
    int isRel = bx >= nodeBlocks;
    int rows = isRel ? R : N;
    int row0 = (isRel ? bx - nodeBlocks : bx) * 64;
    const void* A = isRel ? rel : node;

    int tid = threadIdx.y * 64 + threadIdx.x;
    int lane = threadIdx.x, wv = threadIdx.y;
    int l16 = lane & 15, quad = lane >> 4;
    int ar = row0 + wv * 16 + l16;
    int ar_c = ar < rows ? ar : rows - 1;

    bf16x8 af[4];
#pragma unroll
    for (int kk = 0; kk < 4; kk++) {
        int k = kk * 32 + quad * 8;
        if (f32) {
            const float* Af = (const float*)A + (size_t)ar_c * D + k;
#pragma unroll
            for (int j = 0; j < 8; j++) af[kk][j] = (short)f2bf_bits(Af[j]);
        } else {
            af[kk] = *(const bf16x8*)((const unsigned short*)A + (size_t)ar_c * D + k);
        }
    }

    int cr0 = row0 + wv * 16 + quad * 4;
    int odd = l16 & 1;

    int jpBeg = isRel ? 3 : 0, jpEnd = isRel ? 4 : 3;
    for (int jp = jpBeg; jp < jpEnd; jp++) {
        int qIdx, tIdx;
        unsigned* O = nullptr;
        switch (jp) {
            case 0: qIdx = 0; tIdx = 1; O = nodeST; break;
            case 1: qIdx = 2; tIdx = 3; O = nodeDT; break;
            case 2: qIdx = 4; tIdx = 5; break;  // loopW/evoW pair
            default: qIdx = 6; tIdx = 7; O = relRT; break;
        }
        f32x4 accQ[8], accT[8];
#pragma unroll
        for (int i = 0; i < 8; i++) {
            accQ[i] = (f32x4){0.f, 0.f, 0.f, 0.f};
            accT[i] = (f32x4){0.f, 0.f, 0.f, 0.f};
        }
        for (int pass = 0; pass < 2; pass++) {
            const unsigned short* g = wT + (size_t)(pass ? tIdx : qIdx) * D * D;
            for (int c = tid; c < 2048; c += 256) {
                int n = c >> 4, kb = c & 15;
                *(bf16x8*)(&Wt[n][kb * 8]) = *(const bf16x8*)(g + n * 128 + kb * 8);
            }
            __syncthreads();
            f32x4* acc = pass ? accT : accQ;
#pragma unroll
            for (int kk = 0; kk < 4; kk++) {
#pragma unroll
                for (int nt = 0; nt < 8; nt++) {
                    bf16x8 bfr = *(const bf16x8*)(&Wt[nt * 16 + l16][kk * 32 + quad * 8]);
                    acc[nt] = __builtin_amdgcn_mfma_f32_16x16x32_bf16(af[kk], bfr, acc[nt], 0, 0, 0);
                }
            }
            __syncthreads();
        }
        // epilogue
        if (jp != 2) {
#pragma unroll
            for (int r = 0; r < 4; r++) {
                int cr = cr0 + r;
#pragma unroll
                for (int nt = 0; nt < 8; nt++) {
                    float vQ = accQ[nt][r], vT = accT[nt][r];
                    float oQ = __shfl_xor(vQ, 1);
                    float oT = __shfl_xor(vT, 1);
                    unsigned w;
                    if (!odd) w = (unsigned)f2bf_bits(vQ) | ((unsigned)f2bf_bits(oQ) << 16);
                    else      w = (unsigned)f2bf_bits(oT) | ((unsigned)f2bf_bits(vT) << 16);
                    if (cr < rows) O[(size_t)cr * 128 + nt * 16 + l16] = w;
                }
            }
        } else {
            // loop pair: both lanes of a couple compute both pair-words,
            // even lane stores the deg-selected one (word p = nt*8 + l16/2)
#pragma unroll
            for (int r = 0; r < 4; r++) {
                int cr = cr0 + r;
                int deg = (cr < rows) ? cnt[cr] : 0;
#pragma unroll
                for (int nt = 0; nt < 8; nt++) {
                    float vL = accQ[nt][r], vE = accT[nt][r];
                    float oL = __shfl_xor(vL, 1);
                    float oE = __shfl_xor(vE, 1);
                    unsigned wl, we;
                    if (!odd) {
                        wl = (unsigned)f2bf_bits(vL) | ((unsigned)f2bf_bits(oL) << 16);
                        we = (unsigned)f2bf_bits(vE) | ((unsigned)f2bf_bits(oE) << 16);
                    } else {
                        wl = (unsigned)f2bf_bits(oL) | ((unsigned)f2bf_bits(vL) << 16);
                        we = (unsigned)f2bf_bits(oE) | ((unsigned)f2bf_bits(vE) << 16);
                    }
                    if (cr < rows && !odd)
                        loopSel[(size_t)cr * 64 + nt * 8 + (l16 >> 1)] = (deg > 0) ? wl : we;
                }
            }
        }
    }
}

// ---- K3: CSR build ----
__global__ void count_kernel(const int* __restrict__ dst, int* __restrict__ cnt, int E) {
    int e = blockIdx.x * blockDim.x + threadIdx.x;
    if (e < E) atomicAdd(&cnt[dst[e]], 1);
}

__global__ void scan_block(const int* __restrict__ cnt, int* __restrict__ offs,
                           int* __restrict__ part, int N) {
    __shared__ int sh[256];
    int tid = threadIdx.x;
    int i = blockIdx.x * 256 + tid;
    int v = (i < N) ? cnt[i] : 0;
    sh[tid] = v;
    __syncthreads();
    for (int o = 1; o < 256; o <<= 1) {
        int t = (tid >= o) ? sh[tid - o] : 0;
        __syncthreads();
        sh[tid] += t;
        __syncthreads();
    }
    if (i < N) offs[i] = sh[tid] - v;
    if (tid == 255) part[blockIdx.x] = sh[255];
}

__global__ void scan_part(int* __restrict__ part, int nb) {
    __shared__ int sh[256];
    int tid = threadIdx.x;
    int v = (tid < nb) ? part[tid] : 0;
    sh[tid] = v;
    __syncthreads();
    for (int o = 1; o < 256; o <<= 1) {
        int t = (tid >= o) ? sh[tid - o] : 0;
        __syncthreads();
        sh[tid] += t;
        __syncthreads();
    }
    if (tid < nb) part[tid] = sh[tid] - v;
}

__global__ void scan_add(int* __restrict__ offs, const int* __restrict__ part,
                         int N, int E) {
    int i = blockIdx.x * 256 + threadIdx.x;
    if (i < N) offs[i] += part[blockIdx.x];
    if (i == 0) offs[N] = E;
}

__global__ void scatter_kernel(const int* __restrict__ src, const int* __restrict__ dst,
                               const int* __restrict__ et, const int* __restrict__ offs,
                               int* __restrict__ cur, unsigned* __restrict__ ePack, int E) {
    int e = blockIdx.x * blockDim.x + threadIdx.x;
    if (e >= E) return;
    int d = dst[e];
    int pos = offs[d] + atomicAdd(&cur[d], 1);
    ePack[pos] = (unsigned)src[e] | ((unsigned)et[e] << 20);
}

// ---- K4: wave-per-node aggregation + layernorm ----
__global__ __launch_bounds__(256) void agg_kernel(
    const int* __restrict__ offs, const unsigned* __restrict__ ePack,
    const uint2* __restrict__ ST, const uint2* __restrict__ RT,
    const uint2* __restrict__ DT, const unsigned* __restrict__ loopSel,
    const void* __restrict__ normv, void* __restrict__ out,
    const int* __restrict__ flag, int N) {
    int n = blockIdx.x * 4 + threadIdx.y;
    if (n >= N) return;
    int f32 = *flag;
    int lane = threadIdx.x;
    int start = offs[n], end = offs[n + 1];
    int deg = end - start;

    unsigned ul = loopSel[(size_t)n * 64 + lane];
    uint2 ud = DT[(size_t)n * 64 + lane];
    float qd0, qd1, td0, td1, acc0, acc1;
    unpk(ud.x, qd0, qd1);
    unpk(ud.y, td0, td1);
    unpk(ul, acc0, acc1);

    float den0 = 0.f, den1 = 0.f, h0 = 0.f, h1 = 0.f;
    for (int e0 = start; e0 < end; e0 += 64) {
        int m = end - e0;
        if (m > 64) m = 64;
        unsigned pk = (lane < m) ? ePack[e0 + lane] : 0u;
        int j = 0;
#define EDGE_LOADS(J, US, UR)                                         \
        unsigned pk_##US = __shfl(pk, (J));                           \
        uint2 US = ST[(size_t)(pk_##US & 0xFFFFFu) * 64 + lane];      \
        uint2 UR = RT[(size_t)(pk_##US >> 20) * 64 + lane];
#define EDGE_MATH(US, UR)                                             \
        {                                                             \
            float qs0, qs1, qr0, qr1, ts0, ts1, tr0, tr1;             \
            unpk(US.x, qs0, qs1); unpk(UR.x, qr0, qr1);               \
            unpk(US.y, ts0, ts1); unpk(UR.y, tr0, tr1);               \
            float q0 = qs0 + qr0 + qd0, q1 = qs1 + qr1 + qd1;         \
            float a0 = q0 > 0.f ? q0 : 0.01f * q0;                    \
            float a1 = q1 > 0.f ? q1 : 0.01f * q1;                    \
            float ex0 = __expf(a0), ex1 = __expf(a1);                 \
            den0 += ex0; den1 += ex1;                                 \
            h0 += ex0 * (ts0 + tr0 + td0);                            \
            h1 += ex1 * (ts1 + tr1 + td1);                            \
        }
        for (; j + 3 < m; j += 4) {
            EDGE_LOADS(j + 0, uA, rA)
            EDGE_LOADS(j + 1, uB, rB)
            EDGE_LOADS(j + 2, uC, rC)
            EDGE_LOADS(j + 3, uD, rD)
            EDGE_MATH(uA, rA)
            EDGE_MATH(uB, rB)
            EDGE_MATH(uC, rC)
            EDGE_MATH(uD, rD)
        }
        for (; j < m; j++) {
            EDGE_LOADS(j, uE, rE)
            EDGE_MATH(uE, rE)
        }
    }

    float x0, x1;
    if (deg > 0) {
        float nrm = ldf(normv, n, f32);
        x0 = h0 / den0 * nrm + acc0;
        x1 = h1 / den1 * nrm + acc1;
    } else {
        x0 = acc0;
        x1 = acc1;
    }

    float s = x0 + x1, ss = x0 * x0 + x1 * x1;
#pragma unroll
    for (int o = 32; o; o >>= 1) {
        s += __shfl_xor(s, o);
        ss += __shfl_xor(ss, o);
    }
    float mu = s * (1.f / 128.f);
    float var = ss * (1.f / 128.f) - mu * mu;
    float rstd = rsqrtf(var + 1e-5f);
    float y0 = (x0 - mu) * rstd, y1 = (x1 - mu) * rstd;

    if (f32) {
        ((float2*)out)[(size_t)n * 64 + lane] = make_float2(y0, y1);
    } else {
        unsigned ob = (unsigned)f2bf_bits(y0) | ((unsigned)f2bf_bits(y1) << 16);
        ((unsigned*)out)[(size_t)n * 64 + lane] = ob;
    }
}

extern "C" void kernel_launch(void* const* d_in, const int* in_sizes, int n_in,
                              void* d_out, int out_size, void* d_ws, size_t ws_size,
                              hipStream_t stream) {
    const void* node = d_in[0];
    const void* rel = d_in[1];
    const void* normv = d_in[2];
    const void* wtrip = d_in[3];
    const void* wquad = d_in[4];
    const void* loopW = d_in[5];
    const void* evoW = d_in[6];
    const int* src = (const int*)d_in[7];
    const int* dst = (const int*)d_in[8];
    const int* et = (const int*)d_in[9];

    int N = in_sizes[0] / D;
    int R = in_sizes[1] / D;
    int E = in_sizes[7];
    int nb = (N + 255) / 256;
    int nodeBlocks = (N + 63) / 64;
    int relBlocks = (R + 63) / 64;

    char* p = (char*)d_ws;
    auto alloc = [&](size_t bytes) -> void* {
        void* r = (void*)p;
        p += (bytes + 255) & ~(size_t)255;
        return r;
    };
    unsigned* nodeST = (unsigned*)alloc((size_t)N * 128 * 4);
    unsigned* nodeDT = (unsigned*)alloc((size_t)N * 128 * 4);
    unsigned* relRT = (unsigned*)alloc((size_t)R * 128 * 4);
    unsigned* loopSel = (unsigned*)alloc((size_t)N * 64 * 4);
    unsigned short* wsqAll = (unsigned short*)alloc((size_t)3 * D * D * 2);
    unsigned short* wT = (unsigned short*)alloc((size_t)8 * D * D * 2);
    int* cnt = (int*)alloc((size_t)2 * N * 4);  // cnt | cur
    int* offs = (int*)alloc((size_t)(N + 1) * 4);
    int* part = (int*)alloc((size_t)(nb + 1) * 4);
    unsigned* ePack = (unsigned*)alloc((size_t)E * 4);
    int* flag = (int*)alloc(4);

    init_kernel<<<256, 256, 0, stream>>>(node, flag, cnt, 2 * N);
    wq_kernel<<<dim3(D, 3), D, 0, stream>>>(wtrip, wquad, wsqAll, flag);
    trans_kernel<<<dim3(8, 16), 256, 0, stream>>>(wtrip, loopW, evoW, wsqAll, wT, flag);
    count_kernel<<<(E + 255) / 256, 256, 0, stream>>>(dst, cnt, E);
    gemm_kernel<<<nodeBlocks + relBlocks, dim3(64, 4), 0, stream>>>(
        node, rel, wT, cnt, nodeST, nodeDT, relRT, loopSel, flag, N, R, nodeBlocks);
    scan_block<<<nb, 256, 0, stream>>>(cnt, offs, part, N);
    scan_part<<<1, 256, 0, stream>>>(part, nb);
    scan_add<<<nb, 256, 0, stream>>>(offs, part, N, E);
    scatter_kernel<<<(E + 255) / 256, 256, 0, stream>>>(src, dst, et, offs, cnt + N,
                                                        ePack, E);
    agg_kernel<<<(N + 3) / 4, dim3(64, 4), 0, stream>>>(
        offs, ePack, (const uint2*)nodeST, (const uint2*)relRT, (const uint2*)nodeDT,
        loopSel, normv, d_out, flag, N);
}